// Round 10
// baseline (214.113 us; speedup 1.0000x reference)
//
#include <hip/hip_runtime.h>
#include <math.h>

#define H_IMG 2160
#define W_IMG 3840
#define SPAN 120          // owned cols per strip (sx*SPAN+1 .. +SPAN; strip 0 also col 0)
#define NSX 32            // 32 * 120 = 3840; wave covers 128 cols
#define HS 8              // output rows per wave
#define WPB 4             // waves per block: block covers 32 rows
#define NSY 68            // 68 * 32 = 2176 >= 2160
#define NBLOCKS (NSX * NSY)   // 2176
#define NBINS 2048
#define RING 4            // LDS row-ring slots per wave
#define SLOT_B 3072       // 512 depth + 512 mask + 2048 rgb (1536 used + 512 pad)

// Async-DMA staged kernel, rev 3: ONLY verified 16-byte full-wave DMA calls.
// R8 failed (NaN): divergent-predicated global_load_lds (removed in R9).
// R9 failed (finite 0.082): used size=12 DMA -- the guide HW-verified only
// size 4 (m03) and 16 (m97); if dwordx3's LDS stride is 16 not 12, rgb rows
// land mis-packed => exactly a finite bounded error. rev 3 stages rgb with two
// 16B calls: A = row bytes 0..1023, B = bytes 1024..1535 + 512B over-read
// (harmless, lands in next row / pad region). B's LDS dest = rgb_base+1024 so
// the row maps LINEARLY rgb_base+byte for all 1536 useful bytes.
// WHY async: 8 register-pipelined schedules all pinned 73-81us; L3-WARM
// dispatches (FETCH~0) run the SAME 74us => not HBM-bound; per-body stall
// ~4-6k cycles implies ~5 serialized memory latencies -- consistent with the
// tight 48-52 VGPR allocation chaining loads through reused addr/dest regs.
// global_load_lds has NO dest regs: 3 calls issue back-to-back, one counted
// vmcnt(6) wait per body (2 rows in flight), ring of 4 row-slots in LDS.
// LDS 48KB/block -> 3 blocks/CU. Edge waves take the proven R7 direct path.
// TRIPWIRE: VGPR>64 / WRITE_SIZE >> 100KB => spill; revert to R7.
__global__ __launch_bounds__(256, 4) void shading_main(
    const float* __restrict__ depth,
    const float* __restrict__ rgb,
    const int*   __restrict__ mask,
    const float* __restrict__ lmat,   // [9][3]
    const float* __restrict__ K,      // [3][3]
    float* __restrict__ accum,        // partial {S,C} pairs
    int direct)
{
    __shared__ __align__(16) unsigned char ringmem[WPB][RING][SLOT_B];
    __shared__ float sS[WPB], sC[WPB];

    const int tid  = threadIdx.x;
    const int lane = tid & 63;
    const int wv   = tid >> 6;
    const int sx   = blockIdx.x;
    const int x0   = min(sx * SPAN, W_IMG - 128);  // clamp: window [x0,x0+127] in-image
    const int y0   = blockIdx.y * (WPB * HS) + wv * HS;
    const int colBase  = x0 + 2 * lane;
    const int colBase3 = 3 * colBase;

    // ---- Kinv (adjugate/det; uniform -> SGPRs) ----
    const float m00 = K[0], m01 = K[1], m02 = K[2];
    const float m10 = K[3], m11 = K[4], m12 = K[5];
    const float m20 = K[6], m21 = K[7], m22 = K[8];
    const float det = m00*(m11*m22 - m12*m21)
                    - m01*(m10*m22 - m12*m20)
                    + m02*(m10*m21 - m11*m20);
    const float id  = 1.0f / det;
    const float i00 = (m11*m22 - m12*m21) * id;
    const float i01 = (m02*m21 - m01*m22) * id;
    const float i02 = (m01*m12 - m02*m11) * id;
    const float i10 = (m12*m20 - m10*m22) * id;
    const float i11 = (m00*m22 - m02*m20) * id;
    const float i12 = (m02*m10 - m00*m12) * id;
    const float i20 = (m10*m21 - m11*m20) * id;
    const float i21 = (m01*m20 - m00*m21) * id;
    const float i22 = (m00*m11 - m01*m10) * id;

    float L[27];
    #pragma unroll
    for (int i = 0; i < 27; ++i) L[i] = lmat[i];   // uniform -> s_load

    // ---- output ownership from GLOBAL col (robust to x0 clamp) ----
    float wout[2];
    #pragma unroll
    for (int k = 0; k < 2; ++k) {
        const int c   = colBase + k;
        const int rel = c - sx * SPAN;
        const bool v  = (c < W_IMG) && (rel <= SPAN) && (rel >= 1 || sx == 0);
        wout[k] = v ? 1.0f : 0.0f;
    }
    const float qm1s = (lane == 0) ? 0.0f : 1.0f;

    // ---- ray at (colBase, y0-1); +Kinv col1 per row ----
    float rx = fmaf(i00, (float)colBase, fmaf(i01, (float)(y0 - 1), i02));
    float ry = fmaf(i10, (float)colBase, fmaf(i11, (float)(y0 - 1), i12));
    float rz = fmaf(i20, (float)colBase, fmaf(i21, (float)(y0 - 1), i22));

    const float2 Z2 = make_float2(0.f, 0.f);

    // rolling arithmetic rings (shared by both paths)
    float sA0[2] = {0,0}, sA1[2] = {0,0}, sA2[2] = {0,0};
    float sB0[2] = {0,0}, sB1[2] = {0,0}, sB2[2] = {0,0};
    float qB0[2] = {0,0}, qB1[2] = {0,0}, qB2[2] = {0,0};
    float wB[2]  = {0,0};
    float accS = 0.f, accC = 0.f;

    // interior: prologue row y0-1 >= 0 AND max staged row (y0+9) + overrun < H
    const bool interior = (y0 >= 8) && (y0 + 12 < H_IMG);

    if (interior) {
        unsigned char* const rb = &ringmem[wv][0][0];
        const int offD = 8 * lane;            // depth float2 (row byte 8*lane)
        const int offM = 512 + 8 * lane;      // mask int2
        const int offR = 1024 + 24 * lane;    // rgb 6 floats, LINEAR row bytes

        // per-lane global source pointers (advance by row stride per stage)
        const char* gDM = (lane < 32)
            ? (const char*)(depth + (size_t)(y0 - 1) * W_IMG + x0 + 4 * lane)
            : (const char*)(mask  + (size_t)(y0 - 1) * W_IMG + x0 + 4 * (lane - 32));
        const char* gRA = (const char*)(rgb + (size_t)(y0 - 1) * (3 * W_IMG) + 3 * x0)
                        + 16 * lane;          // rgb row bytes [16l, 16l+15]
        const char* gRB = gRA + 1024;         // rgb row bytes [1024+16l, ..]; 512B over-read

#define STAGE(S) do {                                                          \
        unsigned char* lb_ = rb + (S) * SLOT_B;                                \
        __builtin_amdgcn_global_load_lds((const void*)gDM, (void*)lb_, 16, 0, 0); \
        __builtin_amdgcn_global_load_lds((const void*)gRA, (void*)(lb_ + 1024), 16, 0, 0); \
        __builtin_amdgcn_global_load_lds((const void*)gRB, (void*)(lb_ + 2048), 16, 0, 0); \
        gDM += 15360; gRA += 46080; gRB += 46080;                              \
    } while (0)

        // prologue: rows y0-1, y0, y0+1 -> slots 0..2 (9 calls)
        STAGE(0); STAGE(1); STAGE(2);
        int s_st = 3, s_cu = 0, s_nx = 1;

// One interior body. WN = vmcnt literal, STG = issue next stage, EM = emit.
#define BODYI(WN, STG, EM) do {                                                \
    if (STG) { STAGE(s_st); }                                                  \
    asm volatile("s_waitcnt vmcnt(" #WN ")" ::: "memory");                     \
    __builtin_amdgcn_sched_barrier(0);                                         \
    const unsigned char* lc_ = rb + s_cu * SLOT_B;                             \
    const unsigned char* ln_ = rb + s_nx * SLOT_B;                             \
    const float2 dCv = *(const float2*)(lc_ + offD);                           \
    const float  dRr = *(const float*)(lc_ + offD + 8);                        \
    const float2 dNv = *(const float2*)(ln_ + offD);                           \
    const float2 r0v = *(const float2*)(lc_ + offR);                           \
    const float2 r1v = *(const float2*)(lc_ + offR + 8);                       \
    const float2 r2v = *(const float2*)(lc_ + offR + 16);                      \
    const int2   mv  = *(const int2*)(lc_ + offM);                             \
    /* lane63 right-neighbor read would land in mask area: clamp (w=0 there) */\
    const float dcR = (lane == 63) ? dCv.y : dRr;                              \
    const float dcv[2] = {dCv.x, dCv.y};                                       \
    const float dnv[2] = {dNv.x, dNv.y};                                       \
    const float rrv[6] = {r0v.x, r0v.y, r1v.x, r1v.y, r2v.x, r2v.y};           \
    const int   mmv[2] = {mv.x, mv.y};                                         \
    float qC0[2], qC1[2], qC2[2], wC[2];                                       \
    float rxk = rx, ryk = ry, rzk = rz;                                        \
    _Pragma("unroll")                                                          \
    for (int k = 0; k < 2; ++k) {                                              \
        const float d0 = dcv[k];                                               \
        const float dR = (k == 0) ? dcv[1] : dcR;                              \
        const float dD = dnv[k];                                               \
        const float px = rxk * d0, py = ryk * d0, pz = rzk * d0;               \
        const float ax = (rxk + i00) * dR - px;                                \
        const float ay = (ryk + i10) * dR - py;                                \
        const float az = (rzk + i20) * dR - pz;                                \
        const float bx = (rxk + i01) * dD - px;                                \
        const float by = (ryk + i11) * dD - py;                                \
        const float bz = (rzk + i21) * dD - pz;                                \
        float nx = ay*bz - az*by;                                              \
        float ny = az*bx - ax*bz;                                              \
        float nz = ax*by - ay*bx;                                              \
        const float nn  = nx*nx + ny*ny + nz*nz;                               \
        const float inr = __builtin_amdgcn_rsqf(fmaxf(nn, 1e-24f));            \
        nx *= inr; ny *= inr; nz *= inr;                                       \
        const float h4 = nx*ny, h5 = ny*nz, h7 = nz*nx;                        \
        const float nx2 = nx*nx, ny2 = ny*ny, nz2 = nz*nz;                     \
        const float h6 = 2.f*nz2 - nx2 - ny2;                                  \
        const float h8 = nx2 - ny2;                                            \
        const float B0 = L[0] + ny*L[3] + nz*L[6] + nx*L[9]  + h4*L[12]        \
                       + h5*L[15] + h6*L[18] + h7*L[21] + h8*L[24];            \
        const float B1 = L[1] + ny*L[4] + nz*L[7] + nx*L[10] + h4*L[13]        \
                       + h5*L[16] + h6*L[19] + h7*L[22] + h8*L[25];            \
        const float B2 = L[2] + ny*L[5] + nz*L[8] + nx*L[11] + h4*L[14]        \
                       + h5*L[17] + h6*L[20] + h7*L[23] + h8*L[26];            \
        const float m  = (mmv[k] > 0) ? 1.0f : 0.0f;                           \
        qC0[k] = fmaf(m, B0, -rrv[3*k + 0]);                                   \
        qC1[k] = fmaf(m, B1, -rrv[3*k + 1]);                                   \
        qC2[k] = fmaf(m, B2, -rrv[3*k + 2]);                                   \
        wC[k]  = m * wout[k];                                                  \
        rxk += i00; ryk += i10; rzk += i20;                                    \
    }                                                                          \
    float sC0[2], sC1[2], sC2[2];                                              \
    {                                                                          \
        const float a0 = __shfl_up(qC0[1], 1, 64) * qm1s;                      \
        const float a1 = __shfl_up(qC1[1], 1, 64) * qm1s;                      \
        const float a2 = __shfl_up(qC2[1], 1, 64) * qm1s;                      \
        const float p0 = __shfl_down(qC0[0], 1, 64);                           \
        const float p1 = __shfl_down(qC1[0], 1, 64);                           \
        const float p2 = __shfl_down(qC2[0], 1, 64);                           \
        const float t0 = qC0[0] + qC0[1];                                      \
        sC0[0] = a0 + t0;  sC0[1] = t0 + p0;                                   \
        const float t1 = qC1[0] + qC1[1];                                      \
        sC1[0] = a1 + t1;  sC1[1] = t1 + p1;                                   \
        const float t2 = qC2[0] + qC2[1];                                      \
        sC2[0] = a2 + t2;  sC2[1] = t2 + p2;                                   \
    }                                                                          \
    if (EM) {                                                                  \
        _Pragma("unroll")                                                      \
        for (int k = 0; k < 2; ++k) {                                          \
            const float v0 = sA0[k] + sB0[k] + sC0[k];                         \
            const float v1 = sA1[k] + sB1[k] + sC1[k];                         \
            const float v2 = sA2[k] + sB2[k] + sC2[k];                         \
            const float e0 = fmaf(v0, -(1.f/9.f), qB0[k]);                     \
            const float e1 = fmaf(v1, -(1.f/9.f), qB1[k]);                     \
            const float e2 = fmaf(v2, -(1.f/9.f), qB2[k]);                     \
            const float w  = wB[k];                                            \
            const float t  = e0*e0 + e1*e1 + e2*e2;                            \
            accS += (w > 0.f) ? t : 0.f;   /* select: w=0 can't propagate junk */\
            accC += w;                                                         \
        }                                                                      \
    }                                                                          \
    _Pragma("unroll")                                                          \
    for (int k = 0; k < 2; ++k) {                                              \
        sA0[k] = sB0[k]; sA1[k] = sB1[k]; sA2[k] = sB2[k];                     \
        sB0[k] = sC0[k]; sB1[k] = sC1[k]; sB2[k] = sC2[k];                     \
        qB0[k] = qC0[k]; qB1[k] = qC1[k]; qB2[k] = qC2[k];                     \
        wB[k]  = wC[k];                                                        \
    }                                                                          \
    s_cu = s_nx;                                                               \
    s_nx = (s_nx + 1) & (RING - 1);                                            \
    s_st = (s_st + 1) & (RING - 1);                                            \
    rx += i01; ry += i11; rz += i21;                                           \
} while (0)

        // bodies 0..7: stage row h+3, wait vmcnt(6) (2 rows = 6 calls in flight)
        #pragma unroll 1
        for (int j = 0; j < 8; ++j) {
            const bool em = (j >= 2);
            BODYI(6, 1, em);
        }
        // tail: bodies 8,9 stage nothing; queue drains
        BODYI(3, 0, true);   // j=8: needs stage 9; newest (stage 10) may remain
        BODYI(0, 0, true);   // j=9: needs stage 10
#undef BODYI
#undef STAGE
    } else {
        // ---- edge path: R7 guarded direct-load rolling loop (proven) ----
        float2 dC = Z2, dN = Z2;
        float2 raC = Z2, rbC = Z2, rcC = Z2;
        int2   mC  = make_int2(0, 0);
        if (y0 > 0 && (y0 - 1) < H_IMG) {
            const size_t r = (size_t)(y0 - 1);
            dC  = *(const float2*)(depth + r * W_IMG + colBase);
            raC = *(const float2*)(rgb + r * (3 * W_IMG) + colBase3);
            rbC = *(const float2*)(rgb + r * (3 * W_IMG) + colBase3 + 2);
            rcC = *(const float2*)(rgb + r * (3 * W_IMG) + colBase3 + 4);
            mC  = *(const int2*)(mask + r * W_IMG + colBase);
        }
        if (y0 < H_IMG)
            dN = *(const float2*)(depth + (size_t)y0 * W_IMG + colBase);

        const float* pfD = depth + (size_t)(y0 + 1) * W_IMG + colBase;
        const float* pfR = rgb   + (size_t)y0 * (3 * W_IMG) + colBase3;
        const int*   pfM = mask  + (size_t)y0 * W_IMG + colBase;

        #pragma unroll 1
        for (int j = 0; j < HS + 2; ++j) {
            float2 dP = Z2, raN = Z2, rbN = Z2, rcN = Z2;
            int2   mN = make_int2(0, 0);
            if (y0 + 1 + j < H_IMG) dP = *(const float2*)pfD;
            if (y0 + j < H_IMG) {
                raN = *(const float2*)(pfR);
                rbN = *(const float2*)(pfR + 2);
                rcN = *(const float2*)(pfR + 4);
                mN  = *(const int2*)(pfM);
            }
            pfD += W_IMG; pfR += 3 * W_IMG; pfM += W_IMG;

            const float dcv[2] = {dC.x, dC.y};
            const float dnv[2] = {dN.x, dN.y};
            const float rrv[6] = {raC.x, raC.y, rbC.x, rbC.y, rcC.x, rcC.y};
            const int   mmv[2] = {mC.x, mC.y};
            const float dcR = __shfl_down(dC.x, 1, 64);

            float qC0[2], qC1[2], qC2[2], wC[2];
            float rxk = rx, ryk = ry, rzk = rz;
            #pragma unroll
            for (int k = 0; k < 2; ++k) {
                const float d0 = dcv[k];
                const float dR = (k == 0) ? dcv[1] : dcR;
                const float dD = dnv[k];
                const float px = rxk * d0, py = ryk * d0, pz = rzk * d0;
                const float ax = (rxk + i00) * dR - px;
                const float ay = (ryk + i10) * dR - py;
                const float az = (rzk + i20) * dR - pz;
                const float bx = (rxk + i01) * dD - px;
                const float by = (ryk + i11) * dD - py;
                const float bz = (rzk + i21) * dD - pz;
                float nx = ay*bz - az*by;
                float ny = az*bx - ax*bz;
                float nz = ax*by - ay*bx;
                const float nn  = nx*nx + ny*ny + nz*nz;
                const float inr = __builtin_amdgcn_rsqf(fmaxf(nn, 1e-24f));
                nx *= inr; ny *= inr; nz *= inr;
                const float h4 = nx*ny, h5 = ny*nz, h7 = nz*nx;
                const float nx2 = nx*nx, ny2 = ny*ny, nz2 = nz*nz;
                const float h6 = 2.f*nz2 - nx2 - ny2;
                const float h8 = nx2 - ny2;
                const float B0 = L[0] + ny*L[3] + nz*L[6] + nx*L[9]  + h4*L[12] + h5*L[15] + h6*L[18] + h7*L[21] + h8*L[24];
                const float B1 = L[1] + ny*L[4] + nz*L[7] + nx*L[10] + h4*L[13] + h5*L[16] + h6*L[19] + h7*L[22] + h8*L[25];
                const float B2 = L[2] + ny*L[5] + nz*L[8] + nx*L[11] + h4*L[14] + h5*L[17] + h6*L[20] + h7*L[23] + h8*L[26];
                const float m  = (mmv[k] > 0) ? 1.0f : 0.0f;
                qC0[k] = fmaf(m, B0, -rrv[3*k + 0]);
                qC1[k] = fmaf(m, B1, -rrv[3*k + 1]);
                qC2[k] = fmaf(m, B2, -rrv[3*k + 2]);
                wC[k]  = m * wout[k];
                rxk += i00; ryk += i10; rzk += i20;
            }

            float sC0[2], sC1[2], sC2[2];
            {
                const float a0 = __shfl_up(qC0[1], 1, 64) * qm1s;
                const float a1 = __shfl_up(qC1[1], 1, 64) * qm1s;
                const float a2 = __shfl_up(qC2[1], 1, 64) * qm1s;
                const float p0 = __shfl_down(qC0[0], 1, 64);
                const float p1 = __shfl_down(qC1[0], 1, 64);
                const float p2 = __shfl_down(qC2[0], 1, 64);
                const float t0 = qC0[0] + qC0[1];
                sC0[0] = a0 + t0;  sC0[1] = t0 + p0;
                const float t1 = qC1[0] + qC1[1];
                sC1[0] = a1 + t1;  sC1[1] = t1 + p1;
                const float t2 = qC2[0] + qC2[1];
                sC2[0] = a2 + t2;  sC2[1] = t2 + p2;
            }

            if (j >= 2) {
                #pragma unroll
                for (int k = 0; k < 2; ++k) {
                    const float v0 = sA0[k] + sB0[k] + sC0[k];
                    const float v1 = sA1[k] + sB1[k] + sC1[k];
                    const float v2 = sA2[k] + sB2[k] + sC2[k];
                    const float e0 = fmaf(v0, -(1.f/9.f), qB0[k]);
                    const float e1 = fmaf(v1, -(1.f/9.f), qB1[k]);
                    const float e2 = fmaf(v2, -(1.f/9.f), qB2[k]);
                    const float w  = wB[k];
                    accS = fmaf(w, e0*e0 + e1*e1 + e2*e2, accS);
                    accC += w;
                }
            }

            #pragma unroll
            for (int k = 0; k < 2; ++k) {
                sA0[k] = sB0[k]; sA1[k] = sB1[k]; sA2[k] = sB2[k];
                sB0[k] = sC0[k]; sB1[k] = sC1[k]; sB2[k] = sC2[k];
                qB0[k] = qC0[k]; qB1[k] = qC1[k]; qB2[k] = qC2[k];
                wB[k]  = wC[k];
            }
            dC = dN; dN = dP;
            raC = raN; rbC = rbN; rcC = rcN; mC = mN;
            rx += i01; ry += i11; rz += i21;
        }
    }

    // ---- reduction: wave shuffle -> 4-slot LDS -> store/atomic ----
    #pragma unroll
    for (int off = 32; off > 0; off >>= 1) {
        accS += __shfl_down(accS, off, 64);
        accC += __shfl_down(accC, off, 64);
    }
    if (lane == 0) { sS[wv] = accS; sC[wv] = accC; }
    __syncthreads();
    if (tid == 0) {
        const float ts = sS[0] + sS[1] + sS[2] + sS[3];
        const float tc = sC[0] + sC[1] + sC[2] + sC[3];
        const int bid = blockIdx.y * gridDim.x + blockIdx.x;
        if (direct) {
            accum[2*bid + 0] = ts;
            accum[2*bid + 1] = tc;
        } else {
            const int bin = bid & (NBINS - 1);
            atomicAdd(&accum[2*bin + 0], ts);
            atomicAdd(&accum[2*bin + 1], tc);
        }
    }
}

__global__ __launch_bounds__(256) void finalize_kernel(
    const float* __restrict__ part, int n, float* __restrict__ out)
{
    const int tid = threadIdx.x;
    float s = 0.f, c = 0.f;
    for (int i = tid; i < n; i += 256) {
        s += part[2*i + 0];
        c += part[2*i + 1];
    }
    #pragma unroll
    for (int off = 32; off > 0; off >>= 1) {
        s += __shfl_down(s, off, 64);
        c += __shfl_down(c, off, 64);
    }
    __shared__ float sS[4], sC[4];
    const int wid = tid >> 6, lane = tid & 63;
    if (lane == 0) { sS[wid] = s; sC[wid] = c; }
    __syncthreads();
    if (tid == 0) {
        const float ts = sS[0] + sS[1] + sS[2] + sS[3];
        const float tc = sC[0] + sC[1] + sC[2] + sC[3];
        out[0] = ts / (3.0f * tc);
    }
}

extern "C" void kernel_launch(void* const* d_in, const int* in_sizes, int n_in,
                              void* d_out, int out_size, void* d_ws, size_t ws_size,
                              hipStream_t stream) {
    const float* depth = (const float*)d_in[0];   // [2160][3840] f32
    const float* rgb   = (const float*)d_in[1];   // [2160][3840][3] f32
    const int*   mask  = (const int*)  d_in[2];   // [2160][3840] i32
    const float* lmat  = (const float*)d_in[3];   // [9][3] f32
    const float* K     = (const float*)d_in[4];   // [3][3] f32
    float* accum = (float*)d_ws;
    float* out   = (float*)d_out;

    const dim3 grid(NSX, NSY);                    // 32 x 68 = 2176 blocks x 4 waves

    if (ws_size >= (size_t)NBLOCKS * 2 * sizeof(float)) {
        shading_main<<<grid, 256, 0, stream>>>(depth, rgb, mask, lmat, K, accum, 1);
        finalize_kernel<<<1, 256, 0, stream>>>(accum, NBLOCKS, out);
    } else {
        hipMemsetAsync(accum, 0, NBINS * 2 * sizeof(float), stream);
        shading_main<<<grid, 256, 0, stream>>>(depth, rgb, mask, lmat, K, accum, 0);
        finalize_kernel<<<1, 256, 0, stream>>>(accum, NBINS, out);
    }
}